// Round 1
// baseline (384.601 us; speedup 1.0000x reference)
//
#include <hip/hip_runtime.h>
#include <math.h>

#define N_NODES 50000
#define N_EDGES 800000
#define IN_F 256
#define OUT_F 64

// ---------------------------------------------------------------------------
// 1) Degree counting: one thread per edge, int atomics.
// ---------------------------------------------------------------------------
__global__ __launch_bounds__(256) void deg_kernel(const int* __restrict__ src,
                                                  const int* __restrict__ dst,
                                                  int* __restrict__ outdeg,
                                                  int* __restrict__ indeg) {
    int i = blockIdx.x * blockDim.x + threadIdx.x;
    if (i < N_EDGES) {
        atomicAdd(&outdeg[src[i]], 1);
        atomicAdd(&indeg[dst[i]], 1);
    }
}

// ---------------------------------------------------------------------------
// 2) h = (feat * norm_src) @ W.  W staged in LDS (256x64 f32 = 64 KB).
//    Block = 256 threads = 4 waves; each wave computes 8 rows, lane = out col.
// ---------------------------------------------------------------------------
__global__ __launch_bounds__(256) void gemm_kernel(const float* __restrict__ feat,
                                                   const float* __restrict__ W,
                                                   const int* __restrict__ outdeg,
                                                   float* __restrict__ h) {
    __shared__ float Wl[IN_F * OUT_F];  // 64 KB
    {
        const float4* W4 = (const float4*)W;
        float4* Wl4 = (float4*)Wl;
        #pragma unroll
        for (int i = threadIdx.x; i < IN_F * OUT_F / 4; i += 256) Wl4[i] = W4[i];
    }
    __syncthreads();

    const int wave = threadIdx.x >> 6;
    const int lane = threadIdx.x & 63;
    const int rowBase = blockIdx.x * 32 + wave * 8;

    for (int r = 0; r < 8; ++r) {
        const int row = rowBase + r;
        if (row >= N_NODES) break;
        const float norm = rsqrtf(fmaxf((float)outdeg[row], 1.0f));
        const float4* frow = (const float4*)&feat[(size_t)row * IN_F];
        float acc = 0.f;
        #pragma unroll 8
        for (int k4 = 0; k4 < IN_F / 4; ++k4) {
            float4 f = frow[k4];  // broadcast load (all lanes same addr)
            acc = fmaf(f.x, Wl[(k4 * 4 + 0) * OUT_F + lane], acc);
            acc = fmaf(f.y, Wl[(k4 * 4 + 1) * OUT_F + lane], acc);
            acc = fmaf(f.z, Wl[(k4 * 4 + 2) * OUT_F + lane], acc);
            acc = fmaf(f.w, Wl[(k4 * 4 + 3) * OUT_F + lane], acc);
        }
        h[(size_t)row * OUT_F + lane] = acc * norm;
    }
}

// ---------------------------------------------------------------------------
// 3) Scatter (SpMM): one wave per edge, lane = feature dim.
//    Coalesced 256B gather of h[src], 64-lane atomicAdd into out[dst].
// ---------------------------------------------------------------------------
__global__ __launch_bounds__(256) void scatter_kernel(const int* __restrict__ src,
                                                      const int* __restrict__ dst,
                                                      const float* __restrict__ h,
                                                      float* __restrict__ out) {
    const int wid = (int)((blockIdx.x * (size_t)blockDim.x + threadIdx.x) >> 6);
    const int lane = threadIdx.x & 63;
    if (wid >= N_EDGES) return;
    const int s = src[wid];
    const int d = dst[wid];
    const float v = h[(size_t)s * OUT_F + lane];
    atomicAdd(&out[(size_t)d * OUT_F + lane], v);
}

// ---------------------------------------------------------------------------
// 4) Epilogue: out = sigmoid(out * norm_dst + b), in place.
// ---------------------------------------------------------------------------
__global__ __launch_bounds__(256) void final_kernel(float* __restrict__ out,
                                                    const int* __restrict__ indeg,
                                                    const float* __restrict__ b) {
    const int i = blockIdx.x * blockDim.x + threadIdx.x;
    if (i >= N_NODES * OUT_F) return;
    const int row = i >> 6;
    const int col = i & 63;
    const float norm = rsqrtf(fmaxf((float)indeg[row], 1.0f));
    const float x = out[i] * norm + b[col];
    out[i] = 1.0f / (1.0f + expf(-x));
}

// ---------------------------------------------------------------------------
extern "C" void kernel_launch(void* const* d_in, const int* in_sizes, int n_in,
                              void* d_out, int out_size, void* d_ws, size_t ws_size,
                              hipStream_t stream) {
    const float* feat = (const float*)d_in[0];
    const int* src    = (const int*)d_in[1];
    const int* dst    = (const int*)d_in[2];
    const float* W    = (const float*)d_in[3];
    const float* b    = (const float*)d_in[4];
    float* out = (float*)d_out;

    char* ws = (char*)d_ws;
    float* h    = (float*)ws;                                   // 12.8 MB
    int* outdeg = (int*)(ws + (size_t)N_NODES * OUT_F * 4);     // 200 KB
    int* indeg  = outdeg + N_NODES;                             // 200 KB

    // Zero accumulators (d_out is poisoned; we accumulate into it).
    hipMemsetAsync(out, 0, (size_t)N_NODES * OUT_F * 4, stream);
    hipMemsetAsync(outdeg, 0, (size_t)2 * N_NODES * 4, stream);

    deg_kernel<<<(N_EDGES + 255) / 256, 256, 0, stream>>>(src, dst, outdeg, indeg);

    gemm_kernel<<<(N_NODES + 31) / 32, 256, 0, stream>>>(feat, W, outdeg, h);

    scatter_kernel<<<(int)(((size_t)N_EDGES * 64) / 256), 256, 0, stream>>>(src, dst, h, out);

    final_kernel<<<(N_NODES * 64 + 255) / 256, 256, 0, stream>>>(out, indeg, b);
}

// Round 2
// 255.914 us; speedup vs baseline: 1.5029x; 1.5029x over previous
//
#include <hip/hip_runtime.h>
#include <math.h>

#define N_NODES 50000
#define N_EDGES 800000
#define IN_F 256
#define OUT_F 64

// ---------------------------------------------------------------------------
// 1) Degree counting: one thread per edge, int atomics.
// ---------------------------------------------------------------------------
__global__ __launch_bounds__(256) void deg_kernel(const int* __restrict__ src,
                                                  const int* __restrict__ dst,
                                                  int* __restrict__ outdeg,
                                                  int* __restrict__ indeg) {
    int i = blockIdx.x * blockDim.x + threadIdx.x;
    if (i < N_EDGES) {
        atomicAdd(&outdeg[src[i]], 1);
        atomicAdd(&indeg[dst[i]], 1);
    }
}

// ---------------------------------------------------------------------------
// 2) Exclusive scan of indeg -> ptr[0..N], cursor (copy of ptr[0..N-1]).
//    Single block of 1024 threads, chunked, wave shuffles + LDS for carry.
// ---------------------------------------------------------------------------
__global__ __launch_bounds__(1024) void scan_kernel(const int* __restrict__ indeg,
                                                    int* __restrict__ ptr,
                                                    int* __restrict__ cursor) {
    __shared__ int wsum[16];
    __shared__ int carry_s;
    const int t = threadIdx.x;
    const int lane = t & 63;
    const int wave = t >> 6;
    if (t == 0) carry_s = 0;
    __syncthreads();
    for (int base = 0; base < N_NODES; base += 1024) {
        int v = (base + t < N_NODES) ? indeg[base + t] : 0;
        int incl = v;
        #pragma unroll
        for (int d = 1; d < 64; d <<= 1) {
            int u = __shfl_up(incl, d, 64);
            if (lane >= d) incl += u;
        }
        if (lane == 63) wsum[wave] = incl;
        __syncthreads();
        int woff = 0, total = 0;
        #pragma unroll
        for (int i = 0; i < 16; ++i) {
            int s = wsum[i];
            if (i < wave) woff += s;
            total += s;
        }
        const int carry = carry_s;
        const int ex = carry + woff + incl - v;
        if (base + t < N_NODES) { ptr[base + t] = ex; cursor[base + t] = ex; }
        __syncthreads();
        if (t == 0) carry_s = carry + total;
        __syncthreads();
    }
    if (t == 0) ptr[N_NODES] = carry_s;
}

// ---------------------------------------------------------------------------
// 3) Bucket-sort edges by dst: sorted_src[ptr[d] + k] = src of k-th in-edge.
// ---------------------------------------------------------------------------
__global__ __launch_bounds__(256) void sort_kernel(const int* __restrict__ src,
                                                   const int* __restrict__ dst,
                                                   int* __restrict__ cursor,
                                                   int* __restrict__ sorted_src) {
    int e = blockIdx.x * blockDim.x + threadIdx.x;
    if (e < N_EDGES) {
        const int d = dst[e];
        const int idx = atomicAdd(&cursor[d], 1);
        sorted_src[idx] = src[e];
    }
}

// ---------------------------------------------------------------------------
// 4) h = (feat * norm_src) @ W.
//    Wave computes 16 rows x 64 cols; lane = col. W chunk (32 k) in VGPRs,
//    feat read as wave-uniform scalars (s_load path), pure v_fmac inner loop.
// ---------------------------------------------------------------------------
__global__ __launch_bounds__(256) void gemm_kernel(const float* __restrict__ feat,
                                                   const float* __restrict__ W,
                                                   const int* __restrict__ outdeg,
                                                   float* __restrict__ h) {
    const int lane = threadIdx.x & 63;
    const int wave = __builtin_amdgcn_readfirstlane(threadIdx.x >> 6);
    const int rowBase = blockIdx.x * 64 + wave * 16;

    float acc[16];
    #pragma unroll
    for (int r = 0; r < 16; ++r) acc[r] = 0.f;

    #pragma unroll
    for (int k0 = 0; k0 < IN_F; k0 += 32) {
        float w[32];
        #pragma unroll
        for (int kk = 0; kk < 32; ++kk) w[kk] = W[(size_t)(k0 + kk) * OUT_F + lane];
        #pragma unroll
        for (int r = 0; r < 16; ++r) {
            const int row = rowBase + r;
            if (row >= N_NODES) break;
            const float* fp = feat + (size_t)row * IN_F + k0;
            #pragma unroll
            for (int kk = 0; kk < 32; ++kk) acc[r] = fmaf(fp[kk], w[kk], acc[r]);
        }
    }

    #pragma unroll
    for (int r = 0; r < 16; ++r) {
        const int row = rowBase + r;
        if (row >= N_NODES) break;
        const float norm = rsqrtf(fmaxf((float)outdeg[row], 1.0f));
        h[(size_t)row * OUT_F + lane] = acc[r] * norm;
    }
}

// ---------------------------------------------------------------------------
// 5) Gather + epilogue: one wave per dst node, lane = feature dim.
//    No atomics: serial loop over the node's in-edges, coalesced 256B reads.
//    out = sigmoid(acc * norm_dst + b).
// ---------------------------------------------------------------------------
__global__ __launch_bounds__(256) void gather_kernel(const int* __restrict__ ptr,
                                                     const int* __restrict__ sorted_src,
                                                     const float* __restrict__ h,
                                                     const float* __restrict__ b,
                                                     float* __restrict__ out) {
    const int lane = threadIdx.x & 63;
    int nid = (int)((blockIdx.x * (size_t)blockDim.x + threadIdx.x) >> 6);
    if (nid >= N_NODES) return;
    nid = __builtin_amdgcn_readfirstlane(nid);

    const int beg = ptr[nid];
    const int end = ptr[nid + 1];

    float acc0 = 0.f, acc1 = 0.f;
    int e = beg;
    for (; e + 3 < end; e += 4) {
        const int s0 = sorted_src[e + 0];
        const int s1 = sorted_src[e + 1];
        const int s2 = sorted_src[e + 2];
        const int s3 = sorted_src[e + 3];
        const float v0 = h[(size_t)s0 * OUT_F + lane];
        const float v1 = h[(size_t)s1 * OUT_F + lane];
        const float v2 = h[(size_t)s2 * OUT_F + lane];
        const float v3 = h[(size_t)s3 * OUT_F + lane];
        acc0 += v0 + v2;
        acc1 += v1 + v3;
    }
    for (; e < end; ++e) {
        acc0 += h[(size_t)sorted_src[e] * OUT_F + lane];
    }
    float acc = acc0 + acc1;

    const float norm = rsqrtf(fmaxf((float)(end - beg), 1.0f));
    const float x = acc * norm + b[lane];
    out[(size_t)nid * OUT_F + lane] = 1.0f / (1.0f + expf(-x));
}

// ---------------------------------------------------------------------------
extern "C" void kernel_launch(void* const* d_in, const int* in_sizes, int n_in,
                              void* d_out, int out_size, void* d_ws, size_t ws_size,
                              hipStream_t stream) {
    const float* feat = (const float*)d_in[0];
    const int* src    = (const int*)d_in[1];
    const int* dst    = (const int*)d_in[2];
    const float* W    = (const float*)d_in[3];
    const float* b    = (const float*)d_in[4];
    float* out = (float*)d_out;

    char* ws = (char*)d_ws;
    size_t off = 0;
    float* h = (float*)(ws + off);          off += (size_t)N_NODES * OUT_F * 4;  // 12.8 MB
    int* outdeg = (int*)(ws + off);         off += (size_t)N_NODES * 4;
    int* indeg = (int*)(ws + off);          off += (size_t)N_NODES * 4;
    int* ptr = (int*)(ws + off);            off += (size_t)(N_NODES + 1) * 4;
    int* cursor = (int*)(ws + off);         off += (size_t)N_NODES * 4;
    int* sorted_src = (int*)(ws + off);     off += (size_t)N_EDGES * 4;          // 3.2 MB

    // Zero the two degree arrays (contiguous).
    hipMemsetAsync(outdeg, 0, (size_t)2 * N_NODES * 4, stream);

    deg_kernel<<<(N_EDGES + 255) / 256, 256, 0, stream>>>(src, dst, outdeg, indeg);

    scan_kernel<<<1, 1024, 0, stream>>>(indeg, ptr, cursor);

    sort_kernel<<<(N_EDGES + 255) / 256, 256, 0, stream>>>(src, dst, cursor, sorted_src);

    gemm_kernel<<<(N_NODES + 63) / 64, 256, 0, stream>>>(feat, W, outdeg, h);

    gather_kernel<<<(N_NODES * 64 + 255) / 256, 256, 0, stream>>>(ptr, sorted_src, h, b, out);
}

// Round 3
// 227.389 us; speedup vs baseline: 1.6914x; 1.1254x over previous
//
#include <hip/hip_runtime.h>
#include <math.h>

#define N_NODES 50000
#define N_EDGES 800000
#define IN_F 256
#define OUT_F 64
#define TILE_ROWS 32   // feat rows staged per block in gemm

// async global->LDS, 16B per lane, wave-uniform LDS base + lane*16
#define GLOBAL_LOAD_LDS16(lds_ptr, g_ptr)                                      \
    __builtin_amdgcn_global_load_lds(                                          \
        (const __attribute__((address_space(1))) void*)(g_ptr),               \
        (__attribute__((address_space(3))) void*)(lds_ptr), 16, 0, 0)

// ---------------------------------------------------------------------------
// 1) Degree counting: one thread per edge, int atomics.
// ---------------------------------------------------------------------------
__global__ __launch_bounds__(256) void deg_kernel(const int* __restrict__ src,
                                                  const int* __restrict__ dst,
                                                  int* __restrict__ outdeg,
                                                  int* __restrict__ indeg) {
    int i = blockIdx.x * blockDim.x + threadIdx.x;
    if (i < N_EDGES) {
        atomicAdd(&outdeg[src[i]], 1);
        atomicAdd(&indeg[dst[i]], 1);
    }
}

// ---------------------------------------------------------------------------
// 2) Bucket allocation WITHOUT an ordered scan: wave-level prefix sum of
//    indeg + one atomicAdd per wave on a global counter. Bucket order in
//    sorted_src is arbitrary — gather only needs [beg, beg+deg) per node.
// ---------------------------------------------------------------------------
__global__ __launch_bounds__(256) void alloc_kernel(const int* __restrict__ indeg,
                                                    int* __restrict__ ptrB,
                                                    int* __restrict__ cursor,
                                                    int* __restrict__ counter) {
    const int i = blockIdx.x * blockDim.x + threadIdx.x;
    const int lane = threadIdx.x & 63;
    const int v = (i < N_NODES) ? indeg[i] : 0;
    int incl = v;
    #pragma unroll
    for (int d = 1; d < 64; d <<= 1) {
        int u = __shfl_up(incl, d, 64);
        if (lane >= d) incl += u;
    }
    int base = 0;
    if (lane == 63) base = atomicAdd(counter, incl);  // incl@63 == wave total
    base = __shfl(base, 63, 64);
    const int beg = base + incl - v;
    if (i < N_NODES) { ptrB[i] = beg; cursor[i] = beg; }
}

// ---------------------------------------------------------------------------
// 3) Bucket edges by dst: sorted_src[cursor[d]++] = src.
// ---------------------------------------------------------------------------
__global__ __launch_bounds__(256) void sort_kernel(const int* __restrict__ src,
                                                   const int* __restrict__ dst,
                                                   int* __restrict__ cursor,
                                                   int* __restrict__ sorted_src) {
    int e = blockIdx.x * blockDim.x + threadIdx.x;
    if (e < N_EDGES) {
        const int d = dst[e];
        const int idx = atomicAdd(&cursor[d], 1);
        sorted_src[idx] = src[e];
    }
}

// ---------------------------------------------------------------------------
// 4) h = (feat * norm_src) @ W.
//    feat tile (32 rows, 32 KB) staged in LDS via global_load_lds width-16;
//    W in 32-k VGPR chunks (lane = col); broadcast float4 LDS reads.
// ---------------------------------------------------------------------------
__global__ __launch_bounds__(256) void gemm_kernel(const float* __restrict__ feat,
                                                   const float* __restrict__ W,
                                                   const int* __restrict__ outdeg,
                                                   float* __restrict__ h) {
    __shared__ float ftile[TILE_ROWS * IN_F];  // 32 KB
    const int lane = threadIdx.x & 63;
    const int wave = threadIdx.x >> 6;
    const int rowBase = blockIdx.x * TILE_ROWS;

    // Stage: 8 steps x (4 waves x 1024 B) = 32 KB. Clamp OOB lanes to a safe
    // in-bounds address (their rows are never stored).
    const size_t maxOff = (size_t)N_NODES * IN_F - 4;
    #pragma unroll
    for (int s = 0; s < 8; ++s) {
        const int ldsOff = s * 1024 + wave * 256;            // floats
        size_t gOff = (size_t)rowBase * IN_F + ldsOff + lane * 4;
        if (gOff > maxOff) gOff = maxOff;
        GLOBAL_LOAD_LDS16(&ftile[ldsOff], feat + gOff);
    }
    __syncthreads();

    const int r0 = wave * 8;  // this wave's rows within the tile
    float acc[8];
    #pragma unroll
    for (int r = 0; r < 8; ++r) acc[r] = 0.f;

    for (int k0 = 0; k0 < IN_F; k0 += 32) {
        float w[32];
        #pragma unroll
        for (int kk = 0; kk < 32; ++kk)
            w[kk] = W[(size_t)(k0 + kk) * OUT_F + lane];
        #pragma unroll
        for (int r = 0; r < 8; ++r) {
            const float* fp = &ftile[(r0 + r) * IN_F + k0];
            #pragma unroll
            for (int q = 0; q < 8; ++q) {
                const float4 f = *(const float4*)(fp + q * 4);
                acc[r] = fmaf(f.x, w[q * 4 + 0], acc[r]);
                acc[r] = fmaf(f.y, w[q * 4 + 1], acc[r]);
                acc[r] = fmaf(f.z, w[q * 4 + 2], acc[r]);
                acc[r] = fmaf(f.w, w[q * 4 + 3], acc[r]);
            }
        }
    }

    #pragma unroll
    for (int r = 0; r < 8; ++r) {
        const int row = rowBase + r0 + r;
        if (row < N_NODES) {
            const float norm = rsqrtf(fmaxf((float)outdeg[row], 1.0f));
            h[(size_t)row * OUT_F + lane] = acc[r] * norm;
        }
    }
}

// ---------------------------------------------------------------------------
// 5) Gather + epilogue: one wave per dst node, lane = feature dim.
//    8 gathers in flight, 4 accumulators. out = sigmoid(acc*norm_dst + b).
// ---------------------------------------------------------------------------
__global__ __launch_bounds__(256) void gather_kernel(const int* __restrict__ ptrB,
                                                     const int* __restrict__ indeg,
                                                     const int* __restrict__ sorted_src,
                                                     const float* __restrict__ h,
                                                     const float* __restrict__ b,
                                                     float* __restrict__ out) {
    const int lane = threadIdx.x & 63;
    int nid = (int)((blockIdx.x * (size_t)blockDim.x + threadIdx.x) >> 6);
    if (nid >= N_NODES) return;
    nid = __builtin_amdgcn_readfirstlane(nid);

    const int beg = ptrB[nid];
    const int deg = indeg[nid];
    const int end = beg + deg;

    float a0 = 0.f, a1 = 0.f, a2 = 0.f, a3 = 0.f;
    int e = beg;
    for (; e + 7 < end; e += 8) {
        const int s0 = sorted_src[e + 0];
        const int s1 = sorted_src[e + 1];
        const int s2 = sorted_src[e + 2];
        const int s3 = sorted_src[e + 3];
        const int s4 = sorted_src[e + 4];
        const int s5 = sorted_src[e + 5];
        const int s6 = sorted_src[e + 6];
        const int s7 = sorted_src[e + 7];
        const float v0 = h[(size_t)s0 * OUT_F + lane];
        const float v1 = h[(size_t)s1 * OUT_F + lane];
        const float v2 = h[(size_t)s2 * OUT_F + lane];
        const float v3 = h[(size_t)s3 * OUT_F + lane];
        const float v4 = h[(size_t)s4 * OUT_F + lane];
        const float v5 = h[(size_t)s5 * OUT_F + lane];
        const float v6 = h[(size_t)s6 * OUT_F + lane];
        const float v7 = h[(size_t)s7 * OUT_F + lane];
        a0 += v0 + v4;
        a1 += v1 + v5;
        a2 += v2 + v6;
        a3 += v3 + v7;
    }
    for (; e < end; ++e) a0 += h[(size_t)sorted_src[e] * OUT_F + lane];
    const float acc = (a0 + a1) + (a2 + a3);

    const float norm = rsqrtf(fmaxf((float)deg, 1.0f));
    const float x = acc * norm + b[lane];
    out[(size_t)nid * OUT_F + lane] = 1.0f / (1.0f + expf(-x));
}

// ---------------------------------------------------------------------------
extern "C" void kernel_launch(void* const* d_in, const int* in_sizes, int n_in,
                              void* d_out, int out_size, void* d_ws, size_t ws_size,
                              hipStream_t stream) {
    const float* feat = (const float*)d_in[0];
    const int* src    = (const int*)d_in[1];
    const int* dst    = (const int*)d_in[2];
    const float* W    = (const float*)d_in[3];
    const float* b    = (const float*)d_in[4];
    float* out = (float*)d_out;

    char* ws = (char*)d_ws;
    size_t off = 0;
    float* h = (float*)(ws + off);          off += (size_t)N_NODES * OUT_F * 4;  // 12.8 MB
    int* outdeg = (int*)(ws + off);         off += (size_t)N_NODES * 4;
    int* indeg = (int*)(ws + off);          off += (size_t)N_NODES * 4;
    int* counter = (int*)(ws + off);        off += 16;  // keep 16B alignment
    int* ptrB = (int*)(ws + off);           off += (size_t)N_NODES * 4;
    int* cursor = (int*)(ws + off);         off += (size_t)N_NODES * 4;
    int* sorted_src = (int*)(ws + off);     off += (size_t)N_EDGES * 4;          // 3.2 MB

    // Zero outdeg, indeg, counter (contiguous).
    hipMemsetAsync(outdeg, 0, (size_t)2 * N_NODES * 4 + 16, stream);

    deg_kernel<<<(N_EDGES + 255) / 256, 256, 0, stream>>>(src, dst, outdeg, indeg);

    alloc_kernel<<<(N_NODES + 255) / 256, 256, 0, stream>>>(indeg, ptrB, cursor, counter);

    sort_kernel<<<(N_EDGES + 255) / 256, 256, 0, stream>>>(src, dst, cursor, sorted_src);

    gemm_kernel<<<(N_NODES + TILE_ROWS - 1) / TILE_ROWS, 256, 0, stream>>>(feat, W, outdeg, h);

    gather_kernel<<<(N_NODES * 64 + 255) / 256, 256, 0, stream>>>(ptrB, indeg, sorted_src, h, b, out);
}